// Round 11
// baseline (166.210 us; speedup 1.0000x reference)
//
#include <hip/hip_runtime.h>

#define BB 2
#define NN 16
#define LQ 512
#define DKk 64
#define DVv 64
#define DDd 128
#define H2 256
#define NEG_INF -1e9f

// ---------------------------------------------------------------------------
// Stage 1 v2: 2 rows per block, grid 1024, 4 blocks/CU, 16 waves/CU.
// Per-(row,g) fp64 chain unchanged -> bit-identical U/W outputs.
// ---------------------------------------------------------------------------
__global__ __launch_bounds__(256) void mlp_stage1(
    const float* __restrict__ d0, const float* __restrict__ d1,
    const float* __restrict__ W1, const float* __restrict__ b1,
    double* __restrict__ U64, double* __restrict__ W64,
    float* __restrict__ U32, float* __restrict__ W32)
{
    __shared__ float drow[2][DDd];
    int gid = blockIdx.x;            // half(2) x rowgroup(512)
    int half = gid >> 9;
    int r0 = (gid & 511) * 2;        // rows r0..r0+1 of 1024
    const float* din = half ? d1 : d0;
    int w1off = half ? DDd : 0;
    double* o64 = half ? W64 : U64;
    float* o32 = half ? W32 : U32;
    int t = threadIdx.x;
    drow[t >> 7][t & 127] = din[(size_t)(r0 + (t >> 7)) * DDd + (t & 127)];
    __syncthreads();
    int g = t;
    double acc[2] = {};
#pragma unroll 2
    for (int f = 0; f < DDd; f += 4) {
        double w0 = (double)W1[(w1off + f + 0) * H2 + g];
        double w1 = (double)W1[(w1off + f + 1) * H2 + g];
        double w2 = (double)W1[(w1off + f + 2) * H2 + g];
        double w3 = (double)W1[(w1off + f + 3) * H2 + g];
#pragma unroll
        for (int r = 0; r < 2; ++r) {
            float4 dr = *(const float4*)&drow[r][f];
            acc[r] = fma((double)dr.x, w0, acc[r]);
            acc[r] = fma((double)dr.y, w1, acc[r]);
            acc[r] = fma((double)dr.z, w2, acc[r]);
            acc[r] = fma((double)dr.w, w3, acc[r]);
        }
    }
    double bb = half ? 0.0 : (double)b1[g];
#pragma unroll
    for (int r = 0; r < 2; ++r) {
        double a = acc[r] + bb;
        o64[(size_t)(r0 + r) * H2 + g] = a;
        o32[(size_t)(r0 + r) * H2 + g] = (float)a;
    }
}

// ---------------------------------------------------------------------------
// dec_full v8: thread tile 2i x 2j (4 accs) over a 32x32 block tile
// (16x16 positions), grid 512 = 2 blocks/CU, 8 waves/CU. R9 model: v7 was
// ~4x LDS-pipe-bound (6 b128 per 16 FMA, 1i x 2j). v8 per g: 2 b64 reads
// feed 12 VALU -> ratio 1.7. g-major LDS layout (bank-derived, post-R8
// discipline): Ut[256][36] read at [g][pi*2] = 4 unique addrs (multicast);
// Wt[256][36] read at [g][pj*2] = 16 unique x 8 B = 128 B spread,
// conflict-free. Single staging pass (74 KB LDS, one barrier pair).
// Per-pair fp32 chain ascending-g single-acc -> gaps bit-identical to v7;
// same 2e-2 flag band; same in-block fp64 re-eval (gap64 math/order).
// (R10 bench was an infra failure — resubmitted unchanged.)
// ---------------------------------------------------------------------------
__global__ __launch_bounds__(256, 2) void dec_full(
    const float* __restrict__ U32, const float* __restrict__ W32,
    const double* __restrict__ U64, const double* __restrict__ W64,
    const float* __restrict__ W2, const float* __restrict__ b2,
    float* __restrict__ dec_out)
{
    __shared__ __align__(16) float Ut[H2][36];    // [g][i]  36 KB
    __shared__ __align__(16) float Wt[H2][36];    // [g][j]  36 KB
    __shared__ float gvs[H2];
    __shared__ int lbuf[1024];
    __shared__ int lcnt;
    int bid = blockIdx.x;            // b(2) x it(16) x jt(16)
    int b  = bid >> 8;
    int i0 = ((bid >> 4) & 15) * 32;
    int j0 = (bid & 15) * 32;
    int t = threadIdx.x;
    gvs[t] = W2[t * 2 + 1] - W2[t * 2];
    if (t == 0) lcnt = 0;
    float bias = b2[1] - b2[0];
    {   // stage U,W transposed: row = t>>3 (0..31), gq = t&7; 8 f4 each
        int r = t >> 3, gq = t & 7;
        const float* su = U32 + ((size_t)(b * LQ) + i0 + r) * H2;
        const float* sw = W32 + ((size_t)(b * LQ) + j0 + r) * H2;
#pragma unroll
        for (int s = 0; s < 8; ++s) {
            int g = gq * 4 + s * 32;
            float4 u4 = *(const float4*)(su + g);
            Ut[g + 0][r] = u4.x; Ut[g + 1][r] = u4.y;
            Ut[g + 2][r] = u4.z; Ut[g + 3][r] = u4.w;
            float4 w4 = *(const float4*)(sw + g);
            Wt[g + 0][r] = w4.x; Wt[g + 1][r] = w4.y;
            Wt[g + 2][r] = w4.z; Wt[g + 3][r] = w4.w;
        }
    }
    __syncthreads();
    int pi = t >> 4, pj = t & 15;    // i = i0+pi*2+{0,1}; j = j0+pj*2+{0,1}
    float a00 = 0.f, a01 = 0.f, a10 = 0.f, a11 = 0.f;
#pragma unroll 8
    for (int g = 0; g < H2; ++g) {
        float2 u2 = *(const float2*)&Ut[g][pi * 2];
        float2 w2 = *(const float2*)&Wt[g][pj * 2];
        float gv = gvs[g];
        a00 = fmaf(fmaxf(u2.x + w2.x, 0.f), gv, a00);
        a01 = fmaf(fmaxf(u2.x + w2.y, 0.f), gv, a01);
        a10 = fmaf(fmaxf(u2.y + w2.x, 0.f), gv, a10);
        a11 = fmaf(fmaxf(u2.y + w2.y, 0.f), gv, a11);
    }
    int row0 = b * LQ + i0 + pi * 2;
    float g00 = a00 + bias, g01 = a01 + bias;
    float g10 = a10 + bias, g11 = a11 + bias;
    int jb = j0 + pj * 2;
    *(float2*)&dec_out[(size_t)row0 * LQ + jb] =
        make_float2(g00 > 0.f ? 1.f : 0.f, g01 > 0.f ? 1.f : 0.f);
    *(float2*)&dec_out[(size_t)(row0 + 1) * LQ + jb] =
        make_float2(g10 > 0.f ? 1.f : 0.f, g11 > 0.f ? 1.f : 0.f);
    if (fabsf(g00) < 2e-2f) { int lx = atomicAdd(&lcnt, 1); lbuf[lx] = (row0 << 9) | jb; }
    if (fabsf(g01) < 2e-2f) { int lx = atomicAdd(&lcnt, 1); lbuf[lx] = (row0 << 9) | (jb + 1); }
    if (fabsf(g10) < 2e-2f) { int lx = atomicAdd(&lcnt, 1); lbuf[lx] = ((row0 + 1) << 9) | jb; }
    if (fabsf(g11) < 2e-2f) { int lx = atomicAdd(&lcnt, 1); lbuf[lx] = ((row0 + 1) << 9) | (jb + 1); }
    __syncthreads();
    // ---- in-block fp64 re-eval (gap64's exact math/order), wave per pair ----
    int nloc = lcnt;
    int wv = t >> 6, ln = t & 63;
    for (int x = wv; x < nloc; x += 4) {
        int pij = lbuf[x];
        int j = pij & (LQ - 1);
        int prow = pij >> 9;
        int pb = prow >> 9;
        const double* u = U64 + (size_t)prow * H2;
        const double* w = W64 + ((size_t)(pb * LQ) + j) * H2;
        double acc = 0.0;
        for (int g = ln; g < H2; g += 64) {
            double tv = u[g] + w[g];
            tv = tv > 0.0 ? tv : 0.0;
            acc = fma(tv, (double)W2[g * 2 + 1] - (double)W2[g * 2 + 0], acc);
        }
#pragma unroll
        for (int off = 32; off; off >>= 1) acc += __shfl_xor(acc, off, 64);
        if (ln == 0) {
            acc += (double)b2[1] - (double)b2[0];
            dec_out[(size_t)prow * LQ + j] = acc > 0.0 ? 1.f : 0.f;
        }
    }
}

// ---------------------------------------------------------------------------
// Fused attention v2 (proven R4/R9, ~55 us): byte-identical to R9.
// ---------------------------------------------------------------------------
__global__ __launch_bounds__(256) void fused_attn(
    const float* __restrict__ q, const float* __restrict__ k,
    const float* __restrict__ v, const float* __restrict__ dec,
    float* __restrict__ attn, float* __restrict__ out)
{
    __shared__ __align__(16) float smem[10752];   // 43 KB, phase-overlaid
    float* qT = smem;            // [64][36]   kk-major
    float* kT = smem + 2304;     // [64][132]  kk-major
    float* Ps = smem;            // [32][65]   i-major  (PV phase)
    float* Vs = smem + 2112;     // [64][68]   j-major  (PV phase)
    int bid = blockIdx.x;
    int bn = bid >> 4;
    int i0 = (bid & 15) * 32;
    int b = bn >> 4;
    int t = threadIdx.x;

    {   // stage qT (transpose): i = t>>3, kkq = (t&7)+8*it
        int qi = t >> 3;
        const float* src = q + ((size_t)bn * LQ + i0 + qi) * DKk;
#pragma unroll
        for (int it = 0; it < 2; ++it) {
            int kkq = (t & 7) + it * 8;
            float4 t4 = *(const float4*)(src + kkq * 4);
            qT[(kkq * 4 + 0) * 36 + qi] = t4.x;
            qT[(kkq * 4 + 1) * 36 + qi] = t4.y;
            qT[(kkq * 4 + 2) * 36 + qi] = t4.z;
            qT[(kkq * 4 + 3) * 36 + qi] = t4.w;
        }
    }
    int tiq = t >> 5;            // 0..7  -> i = tiq*4 + r
    int tjq = t & 31;            // 0..31 -> j = c*128 + tjq*4 + cc
    float s[4][4][4];

#pragma unroll
    for (int c = 0; c < 4; ++c) {
        __syncthreads();
        {   // stage kT (transpose): j = (t>>2)+(it&1)*64, kkq = (t&3)+(it>>1)*4
            int kj = t >> 2;
#pragma unroll
            for (int it = 0; it < 8; ++it) {
                int jj = kj + (it & 1) * 64;
                int kkq = (t & 3) + (it >> 1) * 4;
                float4 t4 = *(const float4*)(k + ((size_t)bn * LQ + c * 128 + jj) * DKk + kkq * 4);
                kT[(kkq * 4 + 0) * 132 + jj] = t4.x;
                kT[(kkq * 4 + 1) * 132 + jj] = t4.y;
                kT[(kkq * 4 + 2) * 132 + jj] = t4.z;
                kT[(kkq * 4 + 3) * 132 + jj] = t4.w;
            }
        }
        __syncthreads();
        float acc[4][4] = {};
#pragma unroll 8
        for (int kk = 0; kk < 64; ++kk) {
            float4 a  = *(const float4*)&qT[kk * 36 + tiq * 4];
            float4 bb = *(const float4*)&kT[kk * 132 + tjq * 4];
            acc[0][0] = fmaf(a.x, bb.x, acc[0][0]); acc[0][1] = fmaf(a.x, bb.y, acc[0][1]);
            acc[0][2] = fmaf(a.x, bb.z, acc[0][2]); acc[0][3] = fmaf(a.x, bb.w, acc[0][3]);
            acc[1][0] = fmaf(a.y, bb.x, acc[1][0]); acc[1][1] = fmaf(a.y, bb.y, acc[1][1]);
            acc[1][2] = fmaf(a.y, bb.z, acc[1][2]); acc[1][3] = fmaf(a.y, bb.w, acc[1][3]);
            acc[2][0] = fmaf(a.z, bb.x, acc[2][0]); acc[2][1] = fmaf(a.z, bb.y, acc[2][1]);
            acc[2][2] = fmaf(a.z, bb.z, acc[2][2]); acc[2][3] = fmaf(a.z, bb.w, acc[2][3]);
            acc[3][0] = fmaf(a.w, bb.x, acc[3][0]); acc[3][1] = fmaf(a.w, bb.y, acc[3][1]);
            acc[3][2] = fmaf(a.w, bb.z, acc[3][2]); acc[3][3] = fmaf(a.w, bb.w, acc[3][3]);
        }
#pragma unroll
        for (int r = 0; r < 4; ++r) {
            float4 m4 = *(const float4*)&dec[((size_t)(b * LQ) + i0 + tiq * 4 + r) * LQ + c * 128 + tjq * 4];
            s[c][r][0] = m4.x != 0.f ? acc[r][0] * 0.125f : NEG_INF;
            s[c][r][1] = m4.y != 0.f ? acc[r][1] * 0.125f : NEG_INF;
            s[c][r][2] = m4.z != 0.f ? acc[r][2] * 0.125f : NEG_INF;
            s[c][r][3] = m4.w != 0.f ? acc[r][3] * 0.125f : NEG_INF;
        }
    }
    // softmax over 512 j per row (width-32 shuffle groups = tjq)
#pragma unroll
    for (int r = 0; r < 4; ++r) {
        float m = NEG_INF;
#pragma unroll
        for (int c = 0; c < 4; ++c)
#pragma unroll
            for (int cc = 0; cc < 4; ++cc) m = fmaxf(m, s[c][r][cc]);
#pragma unroll
        for (int off = 1; off < 32; off <<= 1) m = fmaxf(m, __shfl_xor(m, off, 32));
        float sum = 0.f;
#pragma unroll
        for (int c = 0; c < 4; ++c)
#pragma unroll
            for (int cc = 0; cc < 4; ++cc) {
                float e = __expf(s[c][r][cc] - m);
                s[c][r][cc] = e; sum += e;
            }
#pragma unroll
        for (int off = 1; off < 32; off <<= 1) sum += __shfl_xor(sum, off, 32);
        float inv = 1.f / sum;
#pragma unroll
        for (int c = 0; c < 4; ++c)
#pragma unroll
            for (int cc = 0; cc < 4; ++cc) s[c][r][cc] *= inv;
    }
#pragma unroll
    for (int c = 0; c < 4; ++c)
#pragma unroll
        for (int r = 0; r < 4; ++r) {
            float4 wv = make_float4(s[c][r][0], s[c][r][1], s[c][r][2], s[c][r][3]);
            *(float4*)&attn[((size_t)bn * LQ + i0 + tiq * 4 + r) * LQ + c * 128 + tjq * 4] = wv;
        }
    // ---- PV over eight 64-j chunks ----
    int tio = t >> 4;            // 0..15 -> i = tio*2 + rr
    int tdo = t & 15;            // 0..15 -> d = tdo*4
    float o[2][4] = {};
#pragma unroll
    for (int c8 = 0; c8 < 8; ++c8) {
        __syncthreads();
        if ((tjq >> 4) == (c8 & 1)) {      // this thread's s covers this chunk
            int jl4 = tjq & 15;
            int c = c8 >> 1;
#pragma unroll
            for (int r = 0; r < 4; ++r)
#pragma unroll
                for (int cc = 0; cc < 4; ++cc)
                    Ps[(tiq * 4 + r) * 65 + jl4 * 4 + cc] = s[c][r][cc];
        }
        {   // stage Vs: j = t>>2, dq = (t&3)+4*it
            int vj = t >> 2;
#pragma unroll
            for (int it = 0; it < 4; ++it) {
                int dq = (t & 3) + it * 4;
                *(float4*)&Vs[vj * 68 + dq * 4] =
                    *(const float4*)(v + ((size_t)bn * LQ + c8 * 64 + vj) * DVv + dq * 4);
            }
        }
        __syncthreads();
#pragma unroll 8
        for (int jj = 0; jj < 64; ++jj) {
            float p0 = Ps[(tio * 2 + 0) * 65 + jj];
            float p1 = Ps[(tio * 2 + 1) * 65 + jj];
            float4 v4 = *(const float4*)&Vs[jj * 68 + tdo * 4];
            o[0][0] = fmaf(p0, v4.x, o[0][0]); o[0][1] = fmaf(p0, v4.y, o[0][1]);
            o[0][2] = fmaf(p0, v4.z, o[0][2]); o[0][3] = fmaf(p0, v4.w, o[0][3]);
            o[1][0] = fmaf(p1, v4.x, o[1][0]); o[1][1] = fmaf(p1, v4.y, o[1][1]);
            o[1][2] = fmaf(p1, v4.z, o[1][2]); o[1][3] = fmaf(p1, v4.w, o[1][3]);
        }
    }
#pragma unroll
    for (int rr = 0; rr < 2; ++rr)
        *(float4*)&out[((size_t)bn * LQ + i0 + tio * 2 + rr) * DVv + tdo * 4] =
            make_float4(o[rr][0], o[rr][1], o[rr][2], o[rr][3]);
}

// ---------------------------------------------------------------------------
extern "C" void kernel_launch(void* const* d_in, const int* in_sizes, int n_in,
                              void* d_out, int out_size, void* d_ws, size_t ws_size,
                              hipStream_t stream)
{
    const float* q  = (const float*)d_in[0];
    const float* k  = (const float*)d_in[1];
    const float* v  = (const float*)d_in[2];
    const float* d0 = (const float*)d_in[3];
    const float* d1 = (const float*)d_in[4];
    const float* W1 = (const float*)d_in[5];
    const float* b1 = (const float*)d_in[6];
    const float* W2 = (const float*)d_in[7];
    const float* b2 = (const float*)d_in[8];

    float* out  = (float*)d_out;                                  // [2,16,512,64]
    float* attn = out + (size_t)BB * NN * LQ * DVv;               // [2,16,512,512]
    float* dec  = attn + (size_t)BB * NN * LQ * LQ;               // [2,1,512,512]

    // Scratch inside the attn region (32 MB); fully consumed before
    // fused_attn overwrites every attn element (same stream => ordered).
    char* scratch = (char*)attn;
    double* U64 = (double*)(scratch);                             // 0..2 MB
    double* W64 = (double*)(scratch + (2u << 20));                // 2..4 MB
    float*  U32 = (float*) (scratch + (4u << 20));                // 4..5 MB
    float*  W32 = (float*) (scratch + (5u << 20));                // 5..6 MB

    mlp_stage1<<<1024, 256, 0, stream>>>(d0, d1, W1, b1, U64, W64, U32, W32);
    dec_full<<<512, 256, 0, stream>>>(U32, W32, U64, W64, W2, b2, dec);
    fused_attn<<<512, 256, 0, stream>>>(q, k, v, dec, attn, out);
}

// Round 12
// 160.764 us; speedup vs baseline: 1.0339x; 1.0339x over previous
//
#include <hip/hip_runtime.h>

#define BB 2
#define NN 16
#define LQ 512
#define DKk 64
#define DVv 64
#define DDd 128
#define H2 256
#define NEG_INF -1e9f

// ---------------------------------------------------------------------------
// Stage 1 v2 (proven): 2 rows per block, grid 1024, 4 blocks/CU.
// Per-(row,g) fp64 chain unchanged -> bit-identical U/W outputs.
// ---------------------------------------------------------------------------
__global__ __launch_bounds__(256) void mlp_stage1(
    const float* __restrict__ d0, const float* __restrict__ d1,
    const float* __restrict__ W1, const float* __restrict__ b1,
    double* __restrict__ U64, double* __restrict__ W64,
    float* __restrict__ U32, float* __restrict__ W32)
{
    __shared__ float drow[2][DDd];
    int gid = blockIdx.x;            // half(2) x rowgroup(512)
    int half = gid >> 9;
    int r0 = (gid & 511) * 2;        // rows r0..r0+1 of 1024
    const float* din = half ? d1 : d0;
    int w1off = half ? DDd : 0;
    double* o64 = half ? W64 : U64;
    float* o32 = half ? W32 : U32;
    int t = threadIdx.x;
    drow[t >> 7][t & 127] = din[(size_t)(r0 + (t >> 7)) * DDd + (t & 127)];
    __syncthreads();
    int g = t;
    double acc[2] = {};
#pragma unroll 2
    for (int f = 0; f < DDd; f += 4) {
        double w0 = (double)W1[(w1off + f + 0) * H2 + g];
        double w1 = (double)W1[(w1off + f + 1) * H2 + g];
        double w2 = (double)W1[(w1off + f + 2) * H2 + g];
        double w3 = (double)W1[(w1off + f + 3) * H2 + g];
#pragma unroll
        for (int r = 0; r < 2; ++r) {
            float4 dr = *(const float4*)&drow[r][f];
            acc[r] = fma((double)dr.x, w0, acc[r]);
            acc[r] = fma((double)dr.y, w1, acc[r]);
            acc[r] = fma((double)dr.z, w2, acc[r]);
            acc[r] = fma((double)dr.w, w3, acc[r]);
        }
    }
    double bb = half ? 0.0 : (double)b1[g];
#pragma unroll
    for (int r = 0; r < 2; ++r) {
        double a = acc[r] + bb;
        o64[(size_t)(r0 + r) * H2 + g] = a;
        o32[(size_t)(r0 + r) * H2 + g] = (float)a;
    }
}

// ---------------------------------------------------------------------------
// dec_full v8 (kept from R11): 2i x 2j thread tile, g-major LDS, single
// staging pass; in-block fp64 re-eval of |gap|<2e-2 band (gap64's exact
// math/order) -> bit-identical decisions.
// ---------------------------------------------------------------------------
__global__ __launch_bounds__(256, 2) void dec_full(
    const float* __restrict__ U32, const float* __restrict__ W32,
    const double* __restrict__ U64, const double* __restrict__ W64,
    const float* __restrict__ W2, const float* __restrict__ b2,
    float* __restrict__ dec_out)
{
    __shared__ __align__(16) float Ut[H2][36];    // [g][i]  36 KB
    __shared__ __align__(16) float Wt[H2][36];    // [g][j]  36 KB
    __shared__ float gvs[H2];
    __shared__ int lbuf[1024];
    __shared__ int lcnt;
    int bid = blockIdx.x;            // b(2) x it(16) x jt(16)
    int b  = bid >> 8;
    int i0 = ((bid >> 4) & 15) * 32;
    int j0 = (bid & 15) * 32;
    int t = threadIdx.x;
    gvs[t] = W2[t * 2 + 1] - W2[t * 2];
    if (t == 0) lcnt = 0;
    float bias = b2[1] - b2[0];
    {   // stage U,W transposed: row = t>>3 (0..31), gq = t&7; 8 f4 each
        int r = t >> 3, gq = t & 7;
        const float* su = U32 + ((size_t)(b * LQ) + i0 + r) * H2;
        const float* sw = W32 + ((size_t)(b * LQ) + j0 + r) * H2;
#pragma unroll
        for (int s = 0; s < 8; ++s) {
            int g = gq * 4 + s * 32;
            float4 u4 = *(const float4*)(su + g);
            Ut[g + 0][r] = u4.x; Ut[g + 1][r] = u4.y;
            Ut[g + 2][r] = u4.z; Ut[g + 3][r] = u4.w;
            float4 w4 = *(const float4*)(sw + g);
            Wt[g + 0][r] = w4.x; Wt[g + 1][r] = w4.y;
            Wt[g + 2][r] = w4.z; Wt[g + 3][r] = w4.w;
        }
    }
    __syncthreads();
    int pi = t >> 4, pj = t & 15;    // i = i0+pi*2+{0,1}; j = j0+pj*2+{0,1}
    float a00 = 0.f, a01 = 0.f, a10 = 0.f, a11 = 0.f;
#pragma unroll 8
    for (int g = 0; g < H2; ++g) {
        float2 u2 = *(const float2*)&Ut[g][pi * 2];
        float2 w2 = *(const float2*)&Wt[g][pj * 2];
        float gv = gvs[g];
        a00 = fmaf(fmaxf(u2.x + w2.x, 0.f), gv, a00);
        a01 = fmaf(fmaxf(u2.x + w2.y, 0.f), gv, a01);
        a10 = fmaf(fmaxf(u2.y + w2.x, 0.f), gv, a10);
        a11 = fmaf(fmaxf(u2.y + w2.y, 0.f), gv, a11);
    }
    int row0 = b * LQ + i0 + pi * 2;
    float g00 = a00 + bias, g01 = a01 + bias;
    float g10 = a10 + bias, g11 = a11 + bias;
    int jb = j0 + pj * 2;
    *(float2*)&dec_out[(size_t)row0 * LQ + jb] =
        make_float2(g00 > 0.f ? 1.f : 0.f, g01 > 0.f ? 1.f : 0.f);
    *(float2*)&dec_out[(size_t)(row0 + 1) * LQ + jb] =
        make_float2(g10 > 0.f ? 1.f : 0.f, g11 > 0.f ? 1.f : 0.f);
    if (fabsf(g00) < 2e-2f) { int lx = atomicAdd(&lcnt, 1); lbuf[lx] = (row0 << 9) | jb; }
    if (fabsf(g01) < 2e-2f) { int lx = atomicAdd(&lcnt, 1); lbuf[lx] = (row0 << 9) | (jb + 1); }
    if (fabsf(g10) < 2e-2f) { int lx = atomicAdd(&lcnt, 1); lbuf[lx] = ((row0 + 1) << 9) | jb; }
    if (fabsf(g11) < 2e-2f) { int lx = atomicAdd(&lcnt, 1); lbuf[lx] = ((row0 + 1) << 9) | (jb + 1); }
    __syncthreads();
    // ---- in-block fp64 re-eval (gap64's exact math/order), wave per pair ----
    int nloc = lcnt;
    int wv = t >> 6, ln = t & 63;
    for (int x = wv; x < nloc; x += 4) {
        int pij = lbuf[x];
        int j = pij & (LQ - 1);
        int prow = pij >> 9;
        int pb = prow >> 9;
        const double* u = U64 + (size_t)prow * H2;
        const double* w = W64 + ((size_t)(pb * LQ) + j) * H2;
        double acc = 0.0;
        for (int g = ln; g < H2; g += 64) {
            double tv = u[g] + w[g];
            tv = tv > 0.0 ? tv : 0.0;
            acc = fma(tv, (double)W2[g * 2 + 1] - (double)W2[g * 2 + 0], acc);
        }
#pragma unroll
        for (int off = 32; off; off >>= 1) acc += __shfl_xor(acc, off, 64);
        if (ln == 0) {
            acc += (double)b2[1] - (double)b2[0];
            dec_out[(size_t)prow * LQ + j] = acc > 0.0 ? 1.f : 0.f;
        }
    }
}

// ---------------------------------------------------------------------------
// Fused attention v6: QK/softmax/attn-write byte-identical to proven v2.
// PV rebuilt per the validated pipe model (v2 PV was LDS-ISSUE-bound ~34 us:
// 3 LDS instrs per 8 FMA, every thread walks 512 jj). PV v6: thread =
// 4i x 4d x j-half; per jj 1 b128 Pt read (4-addr multicast) + 1 b128 Vs
// read feed 16 FMA; each thread covers 256 jj -> ~14.5 us model.
// Pt[64][32] j-major with XOR quad-swizzle quad' = quad ^ (row&7):
//   writes: banks {0,16}+{8w,8w+4}+4cc spread -> 2-way (free);
//   reads: all lanes same jj -> 4 distinct quads, multicast.
// Vs keeps proven [64][68]. Cross-half reduce via 8KB LDS exchange.
// attn plane bit-identical; out tolerance-checked (order change safe).
// ---------------------------------------------------------------------------
__global__ __launch_bounds__(256) void fused_attn(
    const float* __restrict__ q, const float* __restrict__ k,
    const float* __restrict__ v, const float* __restrict__ dec,
    float* __restrict__ attn, float* __restrict__ out)
{
    __shared__ __align__(16) float smem[10752];   // 43 KB, phase-overlaid
    float* qT = smem;            // [64][36]   kk-major  (QK)
    float* kT = smem + 2304;     // [64][132]  kk-major  (QK)
    float* Pt = smem;            // [64][32]   j-major, quad-swizzled (PV)
    float* Vs = smem + 2112;     // [64][68]   j-major   (PV)
    int bid = blockIdx.x;
    int bn = bid >> 4;
    int i0 = (bid & 15) * 32;
    int b = bn >> 4;
    int t = threadIdx.x;

    {   // stage qT (transpose): i = t>>3, kkq = (t&7)+8*it
        int qi = t >> 3;
        const float* src = q + ((size_t)bn * LQ + i0 + qi) * DKk;
#pragma unroll
        for (int it = 0; it < 2; ++it) {
            int kkq = (t & 7) + it * 8;
            float4 t4 = *(const float4*)(src + kkq * 4);
            qT[(kkq * 4 + 0) * 36 + qi] = t4.x;
            qT[(kkq * 4 + 1) * 36 + qi] = t4.y;
            qT[(kkq * 4 + 2) * 36 + qi] = t4.z;
            qT[(kkq * 4 + 3) * 36 + qi] = t4.w;
        }
    }
    int tiq = t >> 5;            // 0..7  -> i = tiq*4 + r
    int tjq = t & 31;            // 0..31 -> j = c*128 + tjq*4 + cc
    float s[4][4][4];

#pragma unroll
    for (int c = 0; c < 4; ++c) {
        __syncthreads();
        {   // stage kT (transpose): j = (t>>2)+(it&1)*64, kkq = (t&3)+(it>>1)*4
            int kj = t >> 2;
#pragma unroll
            for (int it = 0; it < 8; ++it) {
                int jj = kj + (it & 1) * 64;
                int kkq = (t & 3) + (it >> 1) * 4;
                float4 t4 = *(const float4*)(k + ((size_t)bn * LQ + c * 128 + jj) * DKk + kkq * 4);
                kT[(kkq * 4 + 0) * 132 + jj] = t4.x;
                kT[(kkq * 4 + 1) * 132 + jj] = t4.y;
                kT[(kkq * 4 + 2) * 132 + jj] = t4.z;
                kT[(kkq * 4 + 3) * 132 + jj] = t4.w;
            }
        }
        __syncthreads();
        float acc[4][4] = {};
#pragma unroll 8
        for (int kk = 0; kk < 64; ++kk) {
            float4 a  = *(const float4*)&qT[kk * 36 + tiq * 4];
            float4 bb = *(const float4*)&kT[kk * 132 + tjq * 4];
            acc[0][0] = fmaf(a.x, bb.x, acc[0][0]); acc[0][1] = fmaf(a.x, bb.y, acc[0][1]);
            acc[0][2] = fmaf(a.x, bb.z, acc[0][2]); acc[0][3] = fmaf(a.x, bb.w, acc[0][3]);
            acc[1][0] = fmaf(a.y, bb.x, acc[1][0]); acc[1][1] = fmaf(a.y, bb.y, acc[1][1]);
            acc[1][2] = fmaf(a.y, bb.z, acc[1][2]); acc[1][3] = fmaf(a.y, bb.w, acc[1][3]);
            acc[2][0] = fmaf(a.z, bb.x, acc[2][0]); acc[2][1] = fmaf(a.z, bb.y, acc[2][1]);
            acc[2][2] = fmaf(a.z, bb.z, acc[2][2]); acc[2][3] = fmaf(a.z, bb.w, acc[2][3]);
            acc[3][0] = fmaf(a.w, bb.x, acc[3][0]); acc[3][1] = fmaf(a.w, bb.y, acc[3][1]);
            acc[3][2] = fmaf(a.w, bb.z, acc[3][2]); acc[3][3] = fmaf(a.w, bb.w, acc[3][3]);
        }
#pragma unroll
        for (int r = 0; r < 4; ++r) {
            float4 m4 = *(const float4*)&dec[((size_t)(b * LQ) + i0 + tiq * 4 + r) * LQ + c * 128 + tjq * 4];
            s[c][r][0] = m4.x != 0.f ? acc[r][0] * 0.125f : NEG_INF;
            s[c][r][1] = m4.y != 0.f ? acc[r][1] * 0.125f : NEG_INF;
            s[c][r][2] = m4.z != 0.f ? acc[r][2] * 0.125f : NEG_INF;
            s[c][r][3] = m4.w != 0.f ? acc[r][3] * 0.125f : NEG_INF;
        }
    }
    // softmax over 512 j per row (width-32 shuffle groups = tjq)
#pragma unroll
    for (int r = 0; r < 4; ++r) {
        float m = NEG_INF;
#pragma unroll
        for (int c = 0; c < 4; ++c)
#pragma unroll
            for (int cc = 0; cc < 4; ++cc) m = fmaxf(m, s[c][r][cc]);
#pragma unroll
        for (int off = 1; off < 32; off <<= 1) m = fmaxf(m, __shfl_xor(m, off, 32));
        float sum = 0.f;
#pragma unroll
        for (int c = 0; c < 4; ++c)
#pragma unroll
            for (int cc = 0; cc < 4; ++cc) {
                float e = __expf(s[c][r][cc] - m);
                s[c][r][cc] = e; sum += e;
            }
#pragma unroll
        for (int off = 1; off < 32; off <<= 1) sum += __shfl_xor(sum, off, 32);
        float inv = 1.f / sum;
#pragma unroll
        for (int c = 0; c < 4; ++c)
#pragma unroll
            for (int cc = 0; cc < 4; ++cc) s[c][r][cc] *= inv;
    }
#pragma unroll
    for (int c = 0; c < 4; ++c)
#pragma unroll
        for (int r = 0; r < 4; ++r) {
            float4 wv = make_float4(s[c][r][0], s[c][r][1], s[c][r][2], s[c][r][3]);
            *(float4*)&attn[((size_t)bn * LQ + i0 + tiq * 4 + r) * LQ + c * 128 + tjq * 4] = wv;
        }

    // ---- PV v6: thread = 4i x 4d x j-half; Pt j-major quad-swizzled ----
    int jh = t >> 7;             // 0..1 : j-half of each 64-chunk
    int ih = (t >> 4) & 7;       // i-quad: rows i0 + ih*4 .. +3
    int dh = t & 15;             // d-quad: d = dh*4 .. +3
    float o[4][4] = {};
#pragma unroll
    for (int c8 = 0; c8 < 8; ++c8) {
        __syncthreads();
        if ((tjq >> 4) == (c8 & 1)) {      // owner lanes stage Pt (j-major)
            int jl4 = tjq & 15;
            int c = c8 >> 1;
#pragma unroll
            for (int cc = 0; cc < 4; ++cc) {
                int row = jl4 * 4 + cc;    // local j within chunk
                *(float4*)&Pt[row * 32 + ((tiq ^ (row & 7)) << 2)] =
                    make_float4(s[c][0][cc], s[c][1][cc], s[c][2][cc], s[c][3][cc]);
            }
        }
        {   // stage Vs: j = t>>2, dq = (t&3)+4*it (proven layout)
            int vj = t >> 2;
#pragma unroll
            for (int it = 0; it < 4; ++it) {
                int dq = (t & 3) + it * 4;
                *(float4*)&Vs[vj * 68 + dq * 4] =
                    *(const float4*)(v + ((size_t)bn * LQ + c8 * 64 + vj) * DVv + dq * 4);
            }
        }
        __syncthreads();
#pragma unroll 8
        for (int jx = 0; jx < 32; ++jx) {
            int jj = jh * 32 + jx;
            float4 p4 = *(const float4*)&Pt[jj * 32 + ((ih ^ (jj & 7)) << 2)];
            float4 v4 = *(const float4*)&Vs[jj * 68 + dh * 4];
            o[0][0] = fmaf(p4.x, v4.x, o[0][0]); o[0][1] = fmaf(p4.x, v4.y, o[0][1]);
            o[0][2] = fmaf(p4.x, v4.z, o[0][2]); o[0][3] = fmaf(p4.x, v4.w, o[0][3]);
            o[1][0] = fmaf(p4.y, v4.x, o[1][0]); o[1][1] = fmaf(p4.y, v4.y, o[1][1]);
            o[1][2] = fmaf(p4.y, v4.z, o[1][2]); o[1][3] = fmaf(p4.y, v4.w, o[1][3]);
            o[2][0] = fmaf(p4.z, v4.x, o[2][0]); o[2][1] = fmaf(p4.z, v4.y, o[2][1]);
            o[2][2] = fmaf(p4.z, v4.z, o[2][2]); o[2][3] = fmaf(p4.z, v4.w, o[2][3]);
            o[3][0] = fmaf(p4.w, v4.x, o[3][0]); o[3][1] = fmaf(p4.w, v4.y, o[3][1]);
            o[3][2] = fmaf(p4.w, v4.z, o[3][2]); o[3][3] = fmaf(p4.w, v4.w, o[3][3]);
        }
    }
    // ---- cross-half reduce: jh=1 publishes, jh=0 adds & stores ----
    __syncthreads();
    float* red = smem;           // stride-20 scratch (80 B -> 16B aligned)
    if (jh == 1) {
        int kidx = (ih * 16 + dh) * 20;
#pragma unroll
        for (int rr = 0; rr < 4; ++rr)
            *(float4*)&red[kidx + rr * 4] =
                make_float4(o[rr][0], o[rr][1], o[rr][2], o[rr][3]);
    }
    __syncthreads();
    if (jh == 0) {
        int kidx = (ih * 16 + dh) * 20;
#pragma unroll
        for (int rr = 0; rr < 4; ++rr) {
            float4 p = *(const float4*)&red[kidx + rr * 4];
            *(float4*)&out[((size_t)bn * LQ + i0 + ih * 4 + rr) * DVv + dh * 4] =
                make_float4(o[rr][0] + p.x, o[rr][1] + p.y,
                            o[rr][2] + p.z, o[rr][3] + p.w);
        }
    }
}

// ---------------------------------------------------------------------------
extern "C" void kernel_launch(void* const* d_in, const int* in_sizes, int n_in,
                              void* d_out, int out_size, void* d_ws, size_t ws_size,
                              hipStream_t stream)
{
    const float* q  = (const float*)d_in[0];
    const float* k  = (const float*)d_in[1];
    const float* v  = (const float*)d_in[2];
    const float* d0 = (const float*)d_in[3];
    const float* d1 = (const float*)d_in[4];
    const float* W1 = (const float*)d_in[5];
    const float* b1 = (const float*)d_in[6];
    const float* W2 = (const float*)d_in[7];
    const float* b2 = (const float*)d_in[8];

    float* out  = (float*)d_out;                                  // [2,16,512,64]
    float* attn = out + (size_t)BB * NN * LQ * DVv;               // [2,16,512,512]
    float* dec  = attn + (size_t)BB * NN * LQ * LQ;               // [2,1,512,512]

    // Scratch inside the attn region (32 MB); fully consumed before
    // fused_attn overwrites every attn element (same stream => ordered).
    char* scratch = (char*)attn;
    double* U64 = (double*)(scratch);                             // 0..2 MB
    double* W64 = (double*)(scratch + (2u << 20));                // 2..4 MB
    float*  U32 = (float*) (scratch + (4u << 20));                // 4..5 MB
    float*  W32 = (float*) (scratch + (5u << 20));                // 5..6 MB

    mlp_stage1<<<1024, 256, 0, stream>>>(d0, d1, W1, b1, U64, W64, U32, W32);
    dec_full<<<512, 256, 0, stream>>>(U32, W32, U64, W64, W2, b2, dec);
    fused_attn<<<512, 256, 0, stream>>>(q, k, v, dec, attn, out);
}